// Round 4
// baseline (45.583 us; speedup 1.0000x reference)
//
#include <hip/hip_runtime.h>
#include <math.h>

// PolyaTree: per (point, dim) descend an L=8 complete binary tree.
// LUT approach (R3, passed): split_lut[d][0..126] internal splits,
// value_lut[d][leaf] = sum_path log(b) - log(leaf_len), bit-exact splits.
//
// R4: halve LDS traffic. Within the unrolled dim loop, d is wave-uniform, so
// levels 0-3 (splits sp[0..14]) are read as SCALAR loads from global (SMEM
// pipe) and resolved with cndmask trees; only levels 4-6 + value come from
// LDS gathers (4 reads/point-dim instead of 8).

constexpr int DIMS     = 16;
constexpr int NODES    = 255;   // 2^8 - 1
constexpr int INTERNAL = 127;   // nodes used for branching (levels 0..6)
constexpr int LSTRIDE  = 128;   // per-dim LUT stride

__global__ void build_luts(const float* __restrict__ samples, // (16, 255)
                           float* __restrict__ split_lut,     // (16, 128)
                           float* __restrict__ value_lut)     // (16, 128)
{
#pragma clang fp contract(off)
    int t = blockIdx.x * blockDim.x + threadIdx.x;
    if (t >= DIMS * NODES) return;
    int d = t / NODES;
    int j = t - d * NODES;              // full-tree node index 0..254
    const float* s = samples + d * NODES;

    unsigned key = (unsigned)(j + 1);   // binary: 1 then path bits (0=left)
    int level = 31 - __clz(key);        // 0..7
    float lo = 0.0f, hi = 1.0f, acc = 0.0f;
    int i = 0;
    for (int tb = level - 1; tb >= 0; --tb) {
        float b = s[i];
        acc += logf(b);                 // visited-node log(b) (leaf path use)
        float len = hi - lo;
        float split = lo + b * len;     // EXACT mirror of reference (no fma)
        unsigned bit = (key >> tb) & 1u;
        if (bit == 0u) {
            hi = split;
        } else {
            lo = split;
            hi = split + (1.0f - b) * len;
        }
        i = 2 * i + 1 + (int)bit;
    }
    // now i == j; (lo,hi) is node j's interval, bit-exact vs compute_intervals
    float b = s[j];
    if (j < INTERNAL) {
        float len = hi - lo;
        split_lut[d * LSTRIDE + j] = lo + b * len;
    } else {
        acc += logf(b);                 // leaf node's own log(b) (l = L-1 term)
        value_lut[d * LSTRIDE + (j - INTERNAL)] = acc - logf(hi - lo);
    }
}

__global__ __launch_bounds__(256) void polya_eval(
    const float* __restrict__ x,          // (n, 16) row-major
    const float* __restrict__ split_lut,  // (16*128) global (scalar reads)
    const float* __restrict__ value_lut,  // (16*128)
    float* __restrict__ out,
    int n)
{
    __shared__ float s_split[DIMS * LSTRIDE];   // 8 KB (levels 4-6 used)
    __shared__ float s_value[DIMS * LSTRIDE];   // 8 KB
    for (int i = threadIdx.x; i < DIMS * LSTRIDE; i += 256) {
        s_split[i] = split_lut[i];
        s_value[i] = value_lut[i];
    }
    __syncthreads();

    const int stride = gridDim.x * 256;
    for (int p = blockIdx.x * 256 + threadIdx.x; p < n; p += stride) {
        const float4* xr = reinterpret_cast<const float4*>(x + (size_t)p * DIMS);
        float4 a = xr[0], b4 = xr[1], c = xr[2], e = xr[3];
        float xs[DIMS] = {a.x, a.y, a.z, a.w,  b4.x, b4.y, b4.z, b4.w,
                          c.x, c.y, c.z, c.w,  e.x,  e.y,  e.z,  e.w};
        float acc = 0.0f;
#pragma unroll
        for (int d = 0; d < DIMS; ++d) {
            const float xv = xs[d];
            const float* sp = split_lut + d * LSTRIDE;  // uniform -> s_load
            // levels 0-3 scalar: node = offset + path bits (b0 = MSB)
            const int b0 = (int)(xv > sp[0]);
            const float l1 = b0 ? sp[2] : sp[1];
            const int b1 = (int)(xv > l1);
            const float t0 = b1 ? sp[4]  : sp[3];
            const float t1 = b1 ? sp[6]  : sp[5];
            const float l2 = b0 ? t1 : t0;
            const int b2 = (int)(xv > l2);
            const float u0 = b2 ? sp[8]  : sp[7];
            const float u1 = b2 ? sp[10] : sp[9];
            const float u2 = b2 ? sp[12] : sp[11];
            const float u3 = b2 ? sp[14] : sp[13];
            const float v0 = b1 ? u1 : u0;
            const float v1 = b1 ? u3 : u2;
            const float l3 = b0 ? v1 : v0;
            const int b3 = (int)(xv > l3);
            // level-4 node index = 15 + (b0 b1 b2 b3)
            int idx = 15 + ((b0 << 3) | (b1 << 2) | (b2 << 1) | b3);
            // levels 4-6 via LDS gather (<=2 distinct addr/bank: conflict-free)
            idx = 2 * idx + 1 + (int)(xv > s_split[d * LSTRIDE + idx]);
            idx = 2 * idx + 1 + (int)(xv > s_split[d * LSTRIDE + idx]);
            idx = 2 * idx + 1 + (int)(xv > s_split[d * LSTRIDE + idx]);
            acc += s_value[d * LSTRIDE + (idx - INTERNAL)];
        }
        out[p] = acc * 0.0625f;   // mean over 16 dims (exact /16)
    }
}

extern "C" void kernel_launch(void* const* d_in, const int* in_sizes, int n_in,
                              void* d_out, int out_size, void* d_ws, size_t ws_size,
                              hipStream_t stream) {
    const float* x       = (const float*)d_in[0];   // (n,16) f32
    const float* samples = (const float*)d_in[1];   // (16,255) f32
    // d_in[2] is L == 8 (structure hard-coded / fully unrolled)
    float* out = (float*)d_out;
    const int n = in_sizes[0] / DIMS;

    float* split_lut = (float*)d_ws;                 // 16*128 f32
    float* value_lut = split_lut + DIMS * LSTRIDE;   // 16*128 f32 (16 KB total)

    build_luts<<<(DIMS * NODES + 255) / 256, 256, 0, stream>>>(samples, split_lut, value_lut);

    int blocks = (n + 255) / 256;
    if (blocks > 2048) blocks = 2048;
    polya_eval<<<blocks, 256, 0, stream>>>(x, split_lut, value_lut, out, n);
}

// Round 5
// 37.581 us; speedup vs baseline: 1.2129x; 1.2129x over previous
//
#include <hip/hip_runtime.h>
#include <math.h>

// PolyaTree: per (point, dim) descend an L=8 complete binary tree.
// R5: 2 levels per LDS read. Packed float4 tables, one ds_read_b128 resolves
// two levels: entry = [split(node), split(leftchild), split(rightchild), -].
// Final entry packs [split(lvl6 node), value(leftleaf), value(rightleaf), -].
// 4 x b128 per point-dim (was 8 x b32). Splits bit-exact vs numpy (mul+add,
// contract off) so branch decisions match the reference exactly.

constexpr int DIMS     = 16;
constexpr int NODES    = 255;   // 2^8 - 1

// packed table layout, float4 units:
constexpr int P0_OFF = 0;       // [d]            16 entries  (lvl 0+1)
constexpr int P1_OFF = 16;      // [d][q2]  4/dim 64 entries  (lvl 2+3)
constexpr int P2_OFF = 80;      // [d][q4] 16/dim 256 entries (lvl 4+5)
constexpr int P3_OFF = 336;     // [d][q6] 64/dim 1024 entries(lvl 6 + values)
constexpr int PACK_N = 1360;    // 21.25 KB

// --- exact-mirror node interval descent (validated in R3, absmax 0.03) ---
__device__ void node_lohi(const float* s, int j, float& lo, float& hi, float& acc) {
#pragma clang fp contract(off)
    unsigned key = (unsigned)(j + 1);   // 1 then path bits (0 = left)
    int level = 31 - __clz(key);
    lo = 0.0f; hi = 1.0f; acc = 0.0f;
    int i = 0;
    for (int tb = level - 1; tb >= 0; --tb) {
        float b = s[i];
        acc += logf(b);
        float len = hi - lo;
        float split = lo + b * len;     // EXACT mirror of reference (no fma)
        unsigned bit = (key >> tb) & 1u;
        if (bit == 0u) { hi = split; }
        else { lo = split; hi = split + (1.0f - b) * len; }
        i = 2 * i + 1 + (int)bit;
    }
}

__device__ float node_split(const float* s, int j) {
#pragma clang fp contract(off)
    float lo, hi, acc;
    node_lohi(s, j, lo, hi, acc);
    return lo + s[j] * (hi - lo);
}

__device__ float leaf_value(const float* s, int j) {
    float lo, hi, acc;
    node_lohi(s, j, lo, hi, acc);
    return acc + logf(s[j]) - logf(hi - lo);
}

__global__ void pack_build(const float* __restrict__ samples,  // (16,255)
                           float4* __restrict__ pack)          // PACK_N
{
    int t = blockIdx.x * blockDim.x + threadIdx.x;
    if (t >= PACK_N) return;
    float4 e = make_float4(0.f, 0.f, 0.f, 0.f);
    if (t < P1_OFF) {                               // lvl 0+1: t = d
        const float* s = samples + t * NODES;
        e.x = node_split(s, 0);
        e.y = node_split(s, 1);
        e.z = node_split(s, 2);
    } else if (t < P2_OFF) {                        // lvl 2+3
        int u = t - P1_OFF; int d = u >> 2, q = u & 3;
        const float* s = samples + d * NODES;
        e.x = node_split(s, 3 + q);
        e.y = node_split(s, 7 + 2 * q);
        e.z = node_split(s, 8 + 2 * q);
    } else if (t < P3_OFF) {                        // lvl 4+5
        int u = t - P2_OFF; int d = u >> 4, q = u & 15;
        const float* s = samples + d * NODES;
        e.x = node_split(s, 15 + q);
        e.y = node_split(s, 31 + 2 * q);
        e.z = node_split(s, 32 + 2 * q);
    } else {                                        // lvl 6 + leaf values
        int u = t - P3_OFF; int d = u >> 6, q = u & 63;
        const float* s = samples + d * NODES;
        e.x = node_split(s, 63 + q);
        e.y = leaf_value(s, 127 + 2 * q);
        e.z = leaf_value(s, 128 + 2 * q);
    }
    pack[t] = e;
}

__global__ __launch_bounds__(256) void polya_eval(
    const float* __restrict__ x,        // (n,16) row-major
    const float4* __restrict__ pack,    // PACK_N packed entries
    float* __restrict__ out,
    int n)
{
    __shared__ float4 s_pack[PACK_N];   // 21.25 KB
    for (int i = threadIdx.x; i < PACK_N; i += 256) s_pack[i] = pack[i];
    __syncthreads();

    const int stride = gridDim.x * 256;
    for (int p = blockIdx.x * 256 + threadIdx.x; p < n; p += stride) {
        const float4* xr = reinterpret_cast<const float4*>(x + (size_t)p * DIMS);
        float4 a = xr[0], b4 = xr[1], c = xr[2], e4 = xr[3];
        float xs[DIMS] = {a.x, a.y, a.z, a.w,  b4.x, b4.y, b4.z, b4.w,
                          c.x, c.y, c.z, c.w,  e4.x, e4.y, e4.z, e4.w};
        float acc = 0.0f;
#pragma unroll
        for (int d = 0; d < DIMS; ++d) {
            const float xv = xs[d];
            // lvl 0+1 (broadcast read)
            float4 e0 = s_pack[P0_OFF + d];
            int b0 = (int)(xv > e0.x);
            float s1 = b0 ? e0.z : e0.y;
            int q = (b0 << 1) | (int)(xv > s1);
            // lvl 2+3 (4 addresses)
            float4 e1 = s_pack[P1_OFF + d * 4 + q];
            int b2 = (int)(xv > e1.x);
            float s3 = b2 ? e1.z : e1.y;
            q = (q << 2) | (b2 << 1) | (int)(xv > s3);
            // lvl 4+5 (16 addresses)
            float4 e2 = s_pack[P2_OFF + d * 16 + q];
            int b4i = (int)(xv > e2.x);
            float s5 = b4i ? e2.z : e2.y;
            q = (q << 2) | (b4i << 1) | (int)(xv > s5);
            // lvl 6 + value (64 addresses)
            float4 e3 = s_pack[P3_OFF + d * 64 + q];
            acc += (xv > e3.x) ? e3.z : e3.y;
        }
        out[p] = acc * 0.0625f;   // mean over 16 dims (exact /16)
    }
}

extern "C" void kernel_launch(void* const* d_in, const int* in_sizes, int n_in,
                              void* d_out, int out_size, void* d_ws, size_t ws_size,
                              hipStream_t stream) {
    const float* x       = (const float*)d_in[0];   // (n,16) f32
    const float* samples = (const float*)d_in[1];   // (16,255) f32
    // d_in[2] is L == 8 (structure hard-coded / fully unrolled)
    float* out = (float*)d_out;
    const int n = in_sizes[0] / DIMS;

    float4* pack = (float4*)d_ws;                   // 1360 float4 = 21.25 KB

    pack_build<<<(PACK_N + 255) / 256, 256, 0, stream>>>(samples, pack);

    int blocks = (n + 255) / 256;                   // 3907: 1 point/thread
    polya_eval<<<blocks, 256, 0, stream>>>(x, pack, out, n);
}